// Round 14
// baseline (361.932 us; speedup 1.0000x reference)
//
#include <hip/hip_runtime.h>
#include <math.h>

typedef __attribute__((ext_vector_type(8))) short short8;
typedef __attribute__((ext_vector_type(4))) float f32x4;

static constexpr int F_IN = 512;
static constexpr int H1V = 180, H1P = 192;
static constexpr int H2V = 120, H2P = 128;
static constexpr int NC  = 40,  NCP = 64;

__device__ inline unsigned f2bf(float f) {
    unsigned u = __float_as_uint(f);
    return (u + 0x7fffu + ((u >> 16) & 1u)) >> 16;   // RNE
}
__device__ inline unsigned cvtpk(float lo, float hi) {
    unsigned r;
    asm("v_cvt_pk_bf16_f32 %0, %1, %2" : "=v"(r) : "v"(lo), "v"(hi));
    return r;
}
#define BLO(u) __uint_as_float((u) << 16)
#define BHI(u) __uint_as_float((u) & 0xffff0000u)

__device__ inline void gload_lds16(const void* gsrc, void* ldst) {
    __builtin_amdgcn_global_load_lds(
        (const __attribute__((address_space(1))) void*)gsrc,
        (__attribute__((address_space(3))) void*)ldst, 16, 0, 0);
}

// ---------------- init: edge dtype detect + all weight/bias prep -----------
__global__ void k_init(const int* __restrict__ ei, int* __restrict__ flag,
                       const float* __restrict__ W1, const float* __restrict__ W2,
                       const float* __restrict__ W3, const float* __restrict__ b1,
                       const float* __restrict__ b2, const float* __restrict__ b3,
                       unsigned short* __restrict__ W1s, unsigned short* __restrict__ W2s,
                       unsigned short* __restrict__ W3s, float* __restrict__ b1p,
                       float* __restrict__ b2p, float* __restrict__ b3p) {
    if (blockIdx.x < 16) {
        int i = blockIdx.x * 256 + threadIdx.x;
        if (ei[2 * i + 1] != 0) flag[0] = 1;
        return;
    }
    const int n1 = F_IN * H1P;
    const int n2 = n1 + H1P * H2P;
    const int n3 = n2 + H2P * NCP;
    const int n4 = n3 + H1P;
    const int n5 = n4 + H2P;
    const int n6 = n5 + NCP;
    int i = (blockIdx.x - 16) * 256 + threadIdx.x;
    if (i < n1) {
        int k = i / H1P, c = i % H1P;
        float v = (c < H1V) ? W1[k * H1V + c] : 0.0f;
        W1s[(size_t)(k >> 3) * H1P * 8 + c * 8 + (k & 7)] = (unsigned short)f2bf(v);
    } else if (i < n2) {
        int j = i - n1;
        int k = j / H2P, c = j % H2P;
        float v = (k < H1V && c < H2V) ? W2[k * H2V + c] : 0.0f;
        W2s[(size_t)(k >> 3) * H2P * 8 + c * 8 + (k & 7)] = (unsigned short)f2bf(v);
    } else if (i < n3) {
        int j = i - n2;
        int k = j / NCP, c = j % NCP;
        float v = (k < H2V && c < NC) ? W3[k * NC + c] : 0.0f;
        W3s[(size_t)(k >> 3) * NCP * 8 + c * 8 + (k & 7)] = (unsigned short)f2bf(v);
    } else if (i < n4) {
        int c = i - n3;
        b1p[c] = (c < H1V) ? b1[c] : 0.0f;
    } else if (i < n5) {
        int c = i - n4;
        b2p[c] = (c < H2V) ? b2[c] : 0.0f;
    } else if (i < n6) {
        int c = i - n5;
        b3p[c] = (c < NC) ? b3[c] : -1e30f;
    }
}

// ---------------- MEGA-A: gemm1 (raw, int8 rowquant) 1:2 with hist ---------
__global__ __launch_bounds__(256) void k_megaA(const float* __restrict__ X,
                                               const short8* __restrict__ Bs,
                                               signed char* __restrict__ Hq,
                                               float* __restrict__ sc, int M, int gb,
                                               const int* __restrict__ ei, int E,
                                               const int* __restrict__ flag,
                                               int* __restrict__ deg,
                                               int* __restrict__ dst32,
                                               uint2* __restrict__ sr,
                                               int interleave) {
    __shared__ float ldsf[6144];   // 3 x 8 KB (gemm path only)
    int bid;
    bool isGemm;
    if (interleave) {
        int g = blockIdx.x / 3, r = blockIdx.x % 3;
        if (r == 0) { isGemm = true; bid = g; }
        else        { isGemm = false; bid = g * 2 + r - 1; }
    } else {
        isGemm = (int)blockIdx.x < gb;
        bid = isGemm ? blockIdx.x : blockIdx.x - gb;
    }

    if (!isGemm) {
        int e = bid * 256 + threadIdx.x;
        if (e >= E) return;
        bool i64 = (flag[0] == 0);
        int s, d;
        if (i64) { s = ei[2 * e]; d = ei[2 * E + 2 * e]; }
        else     { s = ei[e];     d = ei[E + e]; }
        int r = atomicAdd(&deg[d], 1);
        dst32[e] = d;
        sr[e] = make_uint2((unsigned)s, (unsigned)r);
        return;
    }

    char* lds = (char*)ldsf;
    int t = threadIdx.x;
    int w = t >> 6, l = t & 63;
    int lr = l & 15, kg = l >> 4;
    int row0 = bid * 32;
    int colb = w * 48;

    f32x4 acc[2][3];
#pragma unroll
    for (int m = 0; m < 2; ++m)
#pragma unroll
        for (int nn = 0; nn < 3; ++nn) acc[m][nn] = (f32x4){0.f, 0.f, 0.f, 0.f};

    auto stage = [&](int kb, int buf) {
#pragma unroll
        for (int j = 0; j < 2; ++j) {
            int o = j * 4096 + t * 16;
            int row = o >> 8;
            int col4 = ((o >> 4) & 15) ^ (row & 15);
            int rowg = row0 + row;
            if (rowg >= M) rowg = M - 1;
            gload_lds16(X + (size_t)rowg * F_IN + kb + col4 * 4,
                        lds + buf * 8192 + j * 4096 + w * 1024);
        }
    };

    short8 breg[2][2][3];
    auto loadB = [&](int ts, int pp) {
#pragma unroll
        for (int kk = 0; kk < 2; ++kk)
#pragma unroll
            for (int nn = 0; nn < 3; ++nn)
                breg[pp][kk][nn] =
                    Bs[(size_t)(ts * 8 + kk * 4 + kg) * H1P + colb + nn * 16 + lr];
    };

    auto compute = [&](int cur, int pp) {
#pragma unroll
        for (int kk = 0; kk < 2; ++kk) {
            short8 a[2];
#pragma unroll
            for (int m = 0; m < 2; ++m) {
                int row = m * 16 + lr;
                char* base = lds + cur * 8192 + row * 256;
                int c0 = kk * 8 + kg * 2;
                float4 v0 = *(const float4*)(base + (((c0 + 0) ^ (row & 15)) * 16));
                float4 v1 = *(const float4*)(base + (((c0 + 1) ^ (row & 15)) * 16));
                union { unsigned u[4]; short8 s; } cu;
                cu.u[0] = cvtpk(v0.x, v0.y);
                cu.u[1] = cvtpk(v0.z, v0.w);
                cu.u[2] = cvtpk(v1.x, v1.y);
                cu.u[3] = cvtpk(v1.z, v1.w);
                a[m] = cu.s;
            }
#pragma unroll
            for (int m = 0; m < 2; ++m)
#pragma unroll
                for (int nn = 0; nn < 3; ++nn)
                    acc[m][nn] = __builtin_amdgcn_mfma_f32_16x16x32_bf16(
                        a[m], breg[pp][kk][nn], acc[m][nn], 0, 0, 0);
        }
    };

    stage(0, 0);
    stage(64, 1);
    loadB(0, 0);
    asm volatile("s_waitcnt vmcnt(8)" ::: "memory");
    __builtin_amdgcn_s_barrier();
    __builtin_amdgcn_sched_barrier(0);

#pragma unroll
    for (int ts = 0; ts < 8; ++ts) {
        if (ts < 6) stage((ts + 2) * 64, (ts + 2) % 3);
        if (ts < 7) loadB(ts + 1, (ts + 1) & 1);
        compute(ts % 3, ts & 1);
        if (ts < 7) {
            if (ts < 6) {
                asm volatile("s_waitcnt vmcnt(8)" ::: "memory");
            } else {
                asm volatile("s_waitcnt vmcnt(6)" ::: "memory");
            }
            __builtin_amdgcn_s_barrier();
            __builtin_amdgcn_sched_barrier(0);
        }
    }

    __syncthreads();
    float* rmaxp = (float*)lds;   // [32][4]
#pragma unroll
    for (int m = 0; m < 2; ++m) {
#pragma unroll
        for (int j = 0; j < 4; ++j) {
            int rl = m * 16 + kg * 4 + j;
            float lm = 0.f;
#pragma unroll
            for (int nn = 0; nn < 3; ++nn)
                lm = fmaxf(lm, fabsf(acc[m][nn][j]));
#pragma unroll
            for (int d = 1; d < 16; d <<= 1)
                lm = fmaxf(lm, __shfl_xor(lm, d));
            if (lr == 0) rmaxp[rl * 4 + w] = lm;
        }
    }
    __syncthreads();
#pragma unroll
    for (int m = 0; m < 2; ++m) {
#pragma unroll
        for (int j = 0; j < 4; ++j) {
            int rl = m * 16 + kg * 4 + j;
            int grow = row0 + rl;
            if (grow >= M) continue;
            float rm = fmaxf(fmaxf(rmaxp[rl * 4 + 0], rmaxp[rl * 4 + 1]),
                             fmaxf(rmaxp[rl * 4 + 2], rmaxp[rl * 4 + 3]));
            float inv = (rm > 0.f) ? 127.0f / rm : 0.f;
            if (w == 0 && lr == 0) sc[grow] = rm * (1.0f / 127.0f);
#pragma unroll
            for (int nn = 0; nn < 3; ++nn) {
                float v = acc[m][nn][j] * inv;
                v = fminf(fmaxf(rintf(v), -127.f), 127.f);
                Hq[(size_t)grow * H1P + colb + nn * 16 + lr] = (signed char)(int)v;
            }
        }
    }
}

// ---------------- scan1: prefix blocks + dinv + scd = sc*dinv --------------
__global__ void k_scan1(const int* __restrict__ deg, int* __restrict__ rp,
                        int* __restrict__ bsum, float* __restrict__ dinv,
                        const float* __restrict__ sc, float* __restrict__ scd,
                        int n) {
    __shared__ int s[256];
    int t = threadIdx.x;
    int base = blockIdx.x * 1024 + t * 4;
    int v0 = (base + 0 < n) ? deg[base + 0] : 0;
    int v1 = (base + 1 < n) ? deg[base + 1] : 0;
    int v2 = (base + 2 < n) ? deg[base + 2] : 0;
    int v3 = (base + 3 < n) ? deg[base + 3] : 0;
    if (base + 0 < n) { float d = rsqrtf((float)(v0 + 1)); dinv[base + 0] = d; scd[base + 0] = d * sc[base + 0]; }
    if (base + 1 < n) { float d = rsqrtf((float)(v1 + 1)); dinv[base + 1] = d; scd[base + 1] = d * sc[base + 1]; }
    if (base + 2 < n) { float d = rsqrtf((float)(v2 + 1)); dinv[base + 2] = d; scd[base + 2] = d * sc[base + 2]; }
    if (base + 3 < n) { float d = rsqrtf((float)(v3 + 1)); dinv[base + 3] = d; scd[base + 3] = d * sc[base + 3]; }
    int sum = v0 + v1 + v2 + v3;
    s[t] = sum;
    __syncthreads();
    for (int off = 1; off < 256; off <<= 1) {
        int x = (t >= off) ? s[t - off] : 0;
        __syncthreads();
        s[t] += x;
        __syncthreads();
    }
    int run = s[t] - sum;
    if (t == 255) bsum[blockIdx.x] = s[255];
    if (base + 0 < n) rp[base + 0] = run; run += v0;
    if (base + 1 < n) rp[base + 1] = run; run += v1;
    if (base + 2 < n) rp[base + 2] = run; run += v2;
    if (base + 3 < n) rp[base + 3] = run;
}

// ---------------- scan3: local bsum prefix (scan2 folded in) + finalize ----
__global__ void k_scan3(const int* __restrict__ bsum, int* __restrict__ rp,
                        int n, int E, int nb) {
    __shared__ int s[128], ov[128];
    int t = threadIdx.x;
    if (t < 128) {
        int v = (t < nb) ? bsum[t] : 0;
        s[t] = v; ov[t] = v;
    }
    __syncthreads();
    for (int off = 1; off < 128; off <<= 1) {
        int x = 0;
        if (t < 128 && t >= off) x = s[t - off];
        __syncthreads();
        if (t < 128) s[t] += x;
        __syncthreads();
    }
    int i = blockIdx.x * 256 + t;
    if (i < n) {
        int b = i >> 10;
        rp[i] += s[b] - ov[b];
    } else if (i == n) {
        rp[n] = E;
    }
}

// ---------------- CSR fill: atomic-free, XCD-bucketed ----------------------
__global__ __launch_bounds__(256) void k_fill(const int* __restrict__ dst32,
                                              const uint2* __restrict__ sr, int E,
                                              const int* __restrict__ rp,
                                              int* __restrict__ csr,
                                              int bw, int chunk) {
    int bkt = blockIdx.x & 7;
    int lo = bkt * bw, hi = lo + bw;
    int ch = blockIdx.x >> 3;
    int e0 = ch * chunk;
    int e1 = min(E, e0 + chunk);
    for (int e = e0 + (int)threadIdx.x; e < e1; e += 256) {
        int d = dst32[e];
        if (d >= lo && d < hi) {
            uint2 v = sr[e];
            csr[rp[d] + (int)v.y] = (int)v.x;
        }
    }
}

// ---------------- device bodies for split/fused kernels --------------------
__device__ __forceinline__ void gat1q_body(int i, int tid,
                                           const signed char* __restrict__ Hq,
                                           const float* __restrict__ scd,
                                           const float* __restrict__ dinv,
                                           const int* __restrict__ rp,
                                           const int* __restrict__ csr,
                                           const float* __restrict__ bias,
                                           uint2* __restrict__ out, int n) {
    int l = tid & 63;
    if (i >= n) return;
    bool act = l < 48;
    int c = act ? l : 0;
    const unsigned* Hr = (const unsigned*)(Hq + c * 4);

    float a0, a1, a2, a3;
    {
        unsigned w0 = Hr[(size_t)i * 48];
        float s0 = scd[i];
        a0 = (float)(signed char)(w0) * s0;
        a1 = (float)(signed char)(w0 >> 8) * s0;
        a2 = (float)(signed char)(w0 >> 16) * s0;
        a3 = (float)(signed char)(w0 >> 24) * s0;
    }
    float p0 = 0.f, p1 = 0.f, p2 = 0.f, p3 = 0.f;

    int e0 = rp[i], e1 = rp[i + 1];
    int e = e0;
    for (; e + 7 < e1; e += 8) {
        int s[8];
#pragma unroll
        for (int q = 0; q < 8; ++q) s[q] = csr[e + q];
        float scs[8];
#pragma unroll
        for (int q = 0; q < 8; ++q) scs[q] = scd[s[q]];
        unsigned v[8];
#pragma unroll
        for (int q = 0; q < 8; ++q) v[q] = Hr[(size_t)s[q] * 48];
#pragma unroll
        for (int q = 0; q < 8; q += 2) {
            a0 = fmaf((float)(signed char)(v[q]), scs[q], a0);
            a1 = fmaf((float)(signed char)(v[q] >> 8), scs[q], a1);
            a2 = fmaf((float)(signed char)(v[q] >> 16), scs[q], a2);
            a3 = fmaf((float)(signed char)(v[q] >> 24), scs[q], a3);
            p0 = fmaf((float)(signed char)(v[q + 1]), scs[q + 1], p0);
            p1 = fmaf((float)(signed char)(v[q + 1] >> 8), scs[q + 1], p1);
            p2 = fmaf((float)(signed char)(v[q + 1] >> 16), scs[q + 1], p2);
            p3 = fmaf((float)(signed char)(v[q + 1] >> 24), scs[q + 1], p3);
        }
    }
    for (; e < e1; ++e) {
        int s0 = csr[e];
        float sq = scd[s0];
        unsigned w0 = Hr[(size_t)s0 * 48];
        a0 = fmaf((float)(signed char)(w0), sq, a0);
        a1 = fmaf((float)(signed char)(w0 >> 8), sq, a1);
        a2 = fmaf((float)(signed char)(w0 >> 16), sq, a2);
        a3 = fmaf((float)(signed char)(w0 >> 24), sq, a3);
    }
    a0 += p0; a1 += p1; a2 += p2; a3 += p3;

    float di = dinv[i];
    float4 bb = *(const float4*)(bias + 4 * c);
    float o0 = fmaf(di, a0, bb.x);
    float o1 = fmaf(di, a1, bb.y);
    float o2 = fmaf(di, a2, bb.z);
    float o3 = fmaf(di, a3, bb.w);
    o0 = o0 >= 0.f ? o0 : 0.01f * o0;
    o1 = o1 >= 0.f ? o1 : 0.01f * o1;
    o2 = o2 >= 0.f ? o2 : 0.01f * o2;
    o3 = o3 >= 0.f ? o3 : 0.01f * o3;
    if (act) {
        uint2 r;
        r.x = (f2bf(o1) << 16) | f2bf(o0);
        r.y = (f2bf(o3) << 16) | f2bf(o2);
        out[(size_t)i * 48 + c] = r;
    }
}

// gemm2 BM=64 body: rows [base + bid*64, +64), all 128 cols, K=192, 16KB LDS
__device__ __forceinline__ void gemm2_body(char* lds, int bid, int base,
                                           const unsigned short* __restrict__ A,
                                           const short8* __restrict__ Bs,
                                           const float* __restrict__ dinv,
                                           unsigned short* __restrict__ Hout,
                                           int M) {
    int t = threadIdx.x;
    int w = t >> 6, l = t & 63;
    int lr = l & 15, kg = l >> 4;
    int row0 = base + bid * 64;
    int colb = w * 32;

    f32x4 acc[4][2];
#pragma unroll
    for (int m = 0; m < 4; ++m)
#pragma unroll
        for (int nn = 0; nn < 2; ++nn) acc[m][nn] = (f32x4){0.f, 0.f, 0.f, 0.f};

    auto stage = [&](int kb, int buf) {
#pragma unroll
        for (int j = 0; j < 2; ++j) {
            int o = j * 4096 + t * 16;
            int row = o >> 7;                         // 128 B rows (64 bf16)
            int chunk = ((o >> 4) & 7) ^ (row & 7);
            int rowg = row0 + row;
            if (rowg >= M) rowg = M - 1;
            gload_lds16(A + (size_t)rowg * H1P + kb + chunk * 8,
                        lds + buf * 8192 + o);
        }
    };

    stage(0, 0);
    __syncthreads();

    for (int ts = 0; ts < 3; ++ts) {
        int cur = ts & 1;
        if (ts < 2) stage((ts + 1) * 64, cur ^ 1);
        short8 b[2][2];
#pragma unroll
        for (int kk = 0; kk < 2; ++kk)
#pragma unroll
            for (int nn = 0; nn < 2; ++nn)
                b[kk][nn] = Bs[(size_t)(ts * 8 + kk * 4 + kg) * H2P + colb + nn * 16 + lr];
        short8 a[2][4];
#pragma unroll
        for (int kk = 0; kk < 2; ++kk)
#pragma unroll
            for (int m = 0; m < 4; ++m) {
                int row = m * 16 + lr;
                a[kk][m] = *(const short8*)(lds + cur * 8192 + row * 128 +
                                            (((kk * 4 + kg) ^ (row & 7)) * 16));
            }
#pragma unroll
        for (int kk = 0; kk < 2; ++kk)
#pragma unroll
            for (int m = 0; m < 4; ++m)
#pragma unroll
                for (int nn = 0; nn < 2; ++nn)
                    acc[m][nn] = __builtin_amdgcn_mfma_f32_16x16x32_bf16(a[kk][m], b[kk][nn], acc[m][nn], 0, 0, 0);
        __syncthreads();
    }

#pragma unroll
    for (int m = 0; m < 4; ++m) {
        int r4 = row0 + m * 16 + kg * 4;
#pragma unroll
        for (int j = 0; j < 4; ++j) {
            int grow = r4 + j;
            if (grow < M) {
                float dv = dinv[grow];
#pragma unroll
                for (int nn = 0; nn < 2; ++nn)
                    Hout[(size_t)grow * H2P + colb + nn * 16 + lr] =
                        (unsigned short)f2bf(acc[m][nn][j] * dv);
            }
        }
    }
}

__device__ __forceinline__ void gat2_body(int i, int tid,
                                          const uint2* __restrict__ H,
                                          const float* __restrict__ dinv,
                                          const int* __restrict__ rp,
                                          const int* __restrict__ csr,
                                          const float* __restrict__ bias,
                                          uint2* __restrict__ out, int n) {
    int l = tid & 63;
    int c = l & 31;
    if (i >= n) return;
    const uint2* Hr = H + c;

    float a0, a1, a2, a3;
    {
        uint2 v = Hr[(size_t)i * 32];
        a0 = BLO(v.x); a1 = BHI(v.x); a2 = BLO(v.y); a3 = BHI(v.y);
    }
    float p0 = 0.f, p1 = 0.f, p2 = 0.f, p3 = 0.f;

    int e0 = rp[i], e1 = rp[i + 1];
    int e = e0;
    for (; e + 7 < e1; e += 8) {
        int s[8];
#pragma unroll
        for (int q = 0; q < 8; ++q) s[q] = csr[e + q];
        uint2 v[8];
#pragma unroll
        for (int q = 0; q < 8; ++q) v[q] = Hr[(size_t)s[q] * 32];
#pragma unroll
        for (int q = 0; q < 8; q += 2) {
            a0 += BLO(v[q].x); a1 += BHI(v[q].x); a2 += BLO(v[q].y); a3 += BHI(v[q].y);
            p0 += BLO(v[q + 1].x); p1 += BHI(v[q + 1].x); p2 += BLO(v[q + 1].y); p3 += BHI(v[q + 1].y);
        }
    }
    for (; e < e1; ++e) {
        int s0 = csr[e];
        uint2 va = Hr[(size_t)s0 * 32];
        a0 += BLO(va.x); a1 += BHI(va.x); a2 += BLO(va.y); a3 += BHI(va.y);
    }
    a0 += p0; a1 += p1; a2 += p2; a3 += p3;

    float di = dinv[i];
    float4 bb = *(const float4*)(bias + 4 * c);
    float o0 = fmaf(di, a0, bb.x);
    float o1 = fmaf(di, a1, bb.y);
    float o2 = fmaf(di, a2, bb.z);
    float o3 = fmaf(di, a3, bb.w);
    o0 = o0 >= 0.f ? o0 : 0.01f * o0;
    o1 = o1 >= 0.f ? o1 : 0.01f * o1;
    o2 = o2 >= 0.f ? o2 : 0.01f * o2;
    o3 = o3 >= 0.f ? o3 : 0.01f * o3;
    uint2 r;
    r.x = (f2bf(o1) << 16) | f2bf(o0);
    r.y = (f2bf(o3) << 16) | f2bf(o2);
    out[(size_t)i * 32 + c] = r;
}

__device__ __forceinline__ void kout_body(int bid, int base,
                                          const unsigned short* __restrict__ H,
                                          const short8* __restrict__ Bs,
                                          const float* __restrict__ b3p,
                                          float* __restrict__ out, int M) {
    int t = threadIdx.x;
    int w = t >> 6, l = t & 63;
    int lr = l & 15, kg = l >> 4;
    int row0 = base + bid * 64 + w * 16;

    f32x4 acc[4];
#pragma unroll
    for (int f = 0; f < 4; ++f) acc[f] = (f32x4){0.f, 0.f, 0.f, 0.f};

    int rowa = row0 + lr;
    if (rowa >= M) rowa = M - 1;
    const unsigned short* arow = H + (size_t)rowa * H2P;

#pragma unroll
    for (int ks = 0; ks < 4; ++ks) {
        short8 a = *(const short8*)(arow + ks * 32 + kg * 8);
#pragma unroll
        for (int f = 0; f < 4; ++f) {
            short8 b = Bs[(size_t)(ks * 4 + kg) * NCP + f * 16 + lr];
            acc[f] = __builtin_amdgcn_mfma_f32_16x16x32_bf16(a, b, acc[f], 0, 0, 0);
        }
    }

    float bl[4];
#pragma unroll
    for (int f = 0; f < 4; ++f) bl[f] = b3p[f * 16 + lr];

#pragma unroll
    for (int j = 0; j < 4; ++j) {
        int grow = row0 + kg * 4 + j;
        float lg[4];
#pragma unroll
        for (int f = 0; f < 4; ++f) lg[f] = acc[f][j] + bl[f];
        float m = fmaxf(fmaxf(lg[0], lg[1]), fmaxf(lg[2], lg[3]));
#pragma unroll
        for (int d = 1; d < 16; d <<= 1) m = fmaxf(m, __shfl_xor(m, d));
        float s = expf(lg[0] - m) + expf(lg[1] - m) + expf(lg[2] - m) + expf(lg[3] - m);
#pragma unroll
        for (int d = 1; d < 16; d <<= 1) s += __shfl_xor(s, d);
        float lse = m + logf(s);
        if (grow < M) {
#pragma unroll
            for (int f = 0; f < 4; ++f) {
                int c = f * 16 + lr;
                if (c < NC) out[(size_t)grow * NC + c] = lg[f] - lse;
            }
        }
    }
}

// ---------------- thin kernels over the bodies -----------------------------
__global__ __launch_bounds__(256) void k_gat1q(const signed char* __restrict__ Hq,
                                               const float* __restrict__ scd,
                                               const float* __restrict__ dinv,
                                               const int* __restrict__ rp,
                                               const int* __restrict__ csr,
                                               const float* __restrict__ bias,
                                               uint2* __restrict__ out, int n,
                                               int nbase) {
    int i = nbase + blockIdx.x * 4 + (threadIdx.x >> 6);
    gat1q_body(i, threadIdx.x, Hq, scd, dinv, rp, csr, bias, out, n);
}

__global__ __launch_bounds__(256) void k_gemm2(const unsigned short* __restrict__ A,
                                               const short8* __restrict__ Bs,
                                               const float* __restrict__ dinv,
                                               unsigned short* __restrict__ Hout,
                                               int M, int base) {
    __shared__ char lds[16384];
    gemm2_body(lds, blockIdx.x, base, A, Bs, dinv, Hout, M);
}

__global__ __launch_bounds__(256) void k_gat2(const uint2* __restrict__ H,
                                              const float* __restrict__ dinv,
                                              const int* __restrict__ rp,
                                              const int* __restrict__ csr,
                                              const float* __restrict__ bias,
                                              uint2* __restrict__ out, int n,
                                              int nbase) {
    int l = threadIdx.x & 63;
    int i = nbase + blockIdx.x * 8 + (threadIdx.x >> 6) * 2 + (l >> 5);
    gat2_body(i, threadIdx.x, H, dinv, rp, csr, bias, out, n);
}

__global__ __launch_bounds__(256) void k_out(const unsigned short* __restrict__ H,
                                             const short8* __restrict__ Bs,
                                             const float* __restrict__ b3p,
                                             float* __restrict__ out, int M, int base) {
    kout_body(blockIdx.x, base, H, Bs, b3p, out, M);
}

// MEGA-B: gemm2 rows [0, g2b*64) || gat1q nodes [nh, n)
__global__ __launch_bounds__(256) void k_megaB(const unsigned short* __restrict__ h1agg,
                                               const short8* __restrict__ W2s,
                                               const float* __restrict__ dinv,
                                               unsigned short* __restrict__ h2,
                                               int M, int g2b,
                                               const signed char* __restrict__ Hq,
                                               const float* __restrict__ scd,
                                               const int* __restrict__ rp,
                                               const int* __restrict__ csr,
                                               const float* __restrict__ b1p,
                                               uint2* __restrict__ h1aggout,
                                               int nh) {
    __shared__ char lds[16384];
    if ((int)blockIdx.x < g2b) {
        gemm2_body(lds, blockIdx.x, 0, h1agg, W2s, dinv, h2, M);
    } else {
        int bid = blockIdx.x - g2b;
        int i = nh + bid * 4 + (threadIdx.x >> 6);
        gat1q_body(i, threadIdx.x, Hq, scd, dinv, rp, csr, b1p, h1aggout, M);
    }
}

// MEGA-C: k_out rows [0, kob*64) || gat2 nodes [nh, n)
__global__ __launch_bounds__(256) void k_megaC(const unsigned short* __restrict__ h2agg,
                                               const short8* __restrict__ W3s,
                                               const float* __restrict__ b3p,
                                               float* __restrict__ out, int M, int kob,
                                               const uint2* __restrict__ h2,
                                               const float* __restrict__ dinv,
                                               const int* __restrict__ rp,
                                               const int* __restrict__ csr,
                                               const float* __restrict__ b2p,
                                               uint2* __restrict__ h2aggout,
                                               int nh) {
    if ((int)blockIdx.x < kob) {
        kout_body(blockIdx.x, 0, h2agg, W3s, b3p, out, M);
    } else {
        int bid = blockIdx.x - kob;
        int l = threadIdx.x & 63;
        int i = nh + bid * 8 + (threadIdx.x >> 6) * 2 + (l >> 5);
        gat2_body(i, threadIdx.x, h2, dinv, rp, csr, b2p, h2aggout, M);
    }
}

// ---------------------------------------------------------------------------
extern "C" void kernel_launch(void* const* d_in, const int* in_sizes, int n_in,
                              void* d_out, int out_size, void* d_ws, size_t ws_size,
                              hipStream_t stream) {
    const float* x  = (const float*)d_in[0];
    const int*   ei = (const int*)d_in[1];
    const float* W1 = (const float*)d_in[2];
    const float* b1 = (const float*)d_in[3];
    const float* W2 = (const float*)d_in[4];
    const float* b2 = (const float*)d_in[5];
    const float* W3 = (const float*)d_in[6];
    const float* b3 = (const float*)d_in[7];
    float* outp = (float*)d_out;

    int n = in_sizes[0] / F_IN;   // 100000
    int E = in_sizes[1] / 2;      // 1600000

    char* p = (char*)d_ws;
    auto alloc = [&](size_t bytes) -> char* {
        char* r = p;
        p += (bytes + 511) & ~(size_t)511;
        return r;
    };
    int*            fd     = (int*)alloc((size_t)(n + 1) * 4);
    int*            flag   = fd;
    int*            deg    = fd + 1;
    float*          dinv   = (float*)alloc((size_t)n * 4);
    int*            rp     = (int*)alloc((size_t)(n + 1) * 4);
    int*            bsum   = (int*)alloc(4096);
    int*            dst32  = (int*)alloc((size_t)E * 4);
    uint2*          sr     = (uint2*)alloc((size_t)E * 8);
    int*            csr    = (int*)alloc((size_t)E * 4);
    unsigned short* W1s    = (unsigned short*)alloc((size_t)F_IN * H1P * 2);
    unsigned short* W2s    = (unsigned short*)alloc((size_t)H1P * H2P * 2);
    unsigned short* W3s    = (unsigned short*)alloc((size_t)H2P * NCP * 2);
    float*          b1p    = (float*)alloc(H1P * 4);
    float*          b2p    = (float*)alloc(H2P * 4);
    float*          b3p    = (float*)alloc(NCP * 4);
    signed char*    h1q    = (signed char*)alloc((size_t)n * H1P);
    float*          sc     = (float*)alloc((size_t)n * 4);
    float*          scd    = (float*)alloc((size_t)n * 4);
    unsigned short* h1agg  = (unsigned short*)alloc((size_t)n * H1P * 2);
    unsigned short* h2     = (unsigned short*)alloc((size_t)n * H2P * 2);
    unsigned short* h2agg  = (unsigned short*)alloc((size_t)n * H2P * 2);

    hipMemsetAsync(fd, 0, (size_t)(n + 1) * 4, stream);

    k_init<<<530, 256, 0, stream>>>(ei, flag, W1, W2, W3, b1, b2, b3,
                                    W1s, W2s, W3s, b1p, b2p, b3p);

    int gb = (n + 31) / 32;
    int eb = (E + 255) / 256;
    int interleave = (eb == 2 * gb) ? 1 : 0;
    k_megaA<<<gb + eb, 256, 0, stream>>>(x, (const short8*)W1s, h1q, sc, n, gb,
                                         ei, E, flag, deg, dst32, sr, interleave);

    int nb = (n + 1023) / 1024;
    k_scan1<<<nb, 256, 0, stream>>>(deg, rp, bsum, dinv, sc, scd, n);
    k_scan3<<<(n + 1 + 255) / 256, 256, 0, stream>>>(bsum, rp, n, E, nb);

    int bw = (n + 7) / 8;
    int nch = 256;
    int chunk = (E + nch - 1) / nch;
    k_fill<<<nch * 8, 256, 0, stream>>>(dst32, sr, E, rp, csr, bw, chunk);

    // half-split pipeline
    int nh = (n / 2) & ~7;             // 50000 (multiple of 8)
    int g1lo = nh / 4;                 // 12500 gat1q blocks (lo)
    int g1hi = (n - nh + 3) / 4;       // 12500 (hi)
    int g2lo = nh / 64;                // 781 gemm2 blocks covering rows < nh
    int g2hib = g2lo * 64;             // 49984
    int g2hi = (n - g2hib + 63) / 64;  // 782
    int kolo = nh / 64;                // 781 k_out blocks
    int kohib = kolo * 64;
    int kohi = (n - kohib + 63) / 64;
    int gt2lo = nh / 8;                // 6250
    int gt2hi = (n - nh + 7) / 8;

    // gat1q lo
    k_gat1q<<<g1lo, 256, 0, stream>>>(h1q, scd, dinv, rp, csr, b1p,
                                      (uint2*)h1agg, n, 0);
    // megaB: gemm2(rows < 49984) || gat1q(nodes >= 50000)
    k_megaB<<<g2lo + g1hi, 256, 0, stream>>>(h1agg, (const short8*)W2s, dinv, h2,
                                             n, g2lo, h1q, scd, rp, csr, b1p,
                                             (uint2*)h1agg, nh);
    // gemm2 hi (rows >= 49984)
    k_gemm2<<<g2hi, 256, 0, stream>>>(h1agg, (const short8*)W2s, dinv, h2, n, g2hib);
    // gat2 lo
    k_gat2<<<gt2lo, 256, 0, stream>>>((const uint2*)h2, dinv, rp, csr, b2p,
                                      (uint2*)h2agg, n, 0);
    // megaC: k_out(rows < 49984) || gat2(nodes >= 50000)
    k_megaC<<<kolo + gt2hi, 256, 0, stream>>>(h2agg, (const short8*)W3s, b3p, outp,
                                              n, kolo, (const uint2*)h2, dinv, rp,
                                              csr, b2p, (uint2*)h2agg, nh);
    // k_out hi (rows >= 49984)
    k_out<<<kohi, 256, 0, stream>>>(h2agg, (const short8*)W3s, b3p, outp, n, kohib);
}

// Round 15
// 316.687 us; speedup vs baseline: 1.1429x; 1.1429x over previous
//
#include <hip/hip_runtime.h>
#include <math.h>

typedef __attribute__((ext_vector_type(8))) short short8;
typedef __attribute__((ext_vector_type(4))) float f32x4;

static constexpr int F_IN = 512;
static constexpr int H1V = 180, H1P = 192;
static constexpr int H2V = 120, H2P = 128;
static constexpr int NC  = 40,  NCP = 64;

__device__ inline unsigned f2bf(float f) {
    unsigned u = __float_as_uint(f);
    return (u + 0x7fffu + ((u >> 16) & 1u)) >> 16;   // RNE
}
__device__ inline unsigned cvtpk(float lo, float hi) {
    unsigned r;
    asm("v_cvt_pk_bf16_f32 %0, %1, %2" : "=v"(r) : "v"(lo), "v"(hi));
    return r;
}
#define BLO(u) __uint_as_float((u) << 16)
#define BHI(u) __uint_as_float((u) & 0xffff0000u)

__device__ inline void gload_lds16(const void* gsrc, void* ldst) {
    __builtin_amdgcn_global_load_lds(
        (const __attribute__((address_space(1))) void*)gsrc,
        (__attribute__((address_space(3))) void*)ldst, 16, 0, 0);
}

// ---------------- init: edge dtype detect + all weight/bias prep -----------
__global__ void k_init(const int* __restrict__ ei, int* __restrict__ flag,
                       const float* __restrict__ W1, const float* __restrict__ W2,
                       const float* __restrict__ W3, const float* __restrict__ b1,
                       const float* __restrict__ b2, const float* __restrict__ b3,
                       unsigned short* __restrict__ W1s, unsigned short* __restrict__ W2s,
                       unsigned short* __restrict__ W3s, float* __restrict__ b1p,
                       float* __restrict__ b2p, float* __restrict__ b3p) {
    if (blockIdx.x < 16) {
        int i = blockIdx.x * 256 + threadIdx.x;
        if (ei[2 * i + 1] != 0) flag[0] = 1;
        return;
    }
    const int n1 = F_IN * H1P;
    const int n2 = n1 + H1P * H2P;
    const int n3 = n2 + H2P * NCP;
    const int n4 = n3 + H1P;
    const int n5 = n4 + H2P;
    const int n6 = n5 + NCP;
    int i = (blockIdx.x - 16) * 256 + threadIdx.x;
    if (i < n1) {
        int k = i / H1P, c = i % H1P;
        float v = (c < H1V) ? W1[k * H1V + c] : 0.0f;
        W1s[(size_t)(k >> 3) * H1P * 8 + c * 8 + (k & 7)] = (unsigned short)f2bf(v);
    } else if (i < n2) {
        int j = i - n1;
        int k = j / H2P, c = j % H2P;
        float v = (k < H1V && c < H2V) ? W2[k * H2V + c] : 0.0f;
        W2s[(size_t)(k >> 3) * H2P * 8 + c * 8 + (k & 7)] = (unsigned short)f2bf(v);
    } else if (i < n3) {
        int j = i - n2;
        int k = j / NCP, c = j % NCP;
        float v = (k < H2V && c < NC) ? W3[k * NC + c] : 0.0f;
        W3s[(size_t)(k >> 3) * NCP * 8 + c * 8 + (k & 7)] = (unsigned short)f2bf(v);
    } else if (i < n4) {
        int c = i - n3;
        b1p[c] = (c < H1V) ? b1[c] : 0.0f;
    } else if (i < n5) {
        int c = i - n4;
        b2p[c] = (c < H2V) ? b2[c] : 0.0f;
    } else if (i < n6) {
        int c = i - n5;
        b3p[c] = (c < NC) ? b3[c] : -1e30f;
    }
}

// ---------------- MEGA-A: gemm1 (raw, int8 rowquant) 1:2 with hist ---------
__global__ __launch_bounds__(256) void k_megaA(const float* __restrict__ X,
                                               const short8* __restrict__ Bs,
                                               signed char* __restrict__ Hq,
                                               float* __restrict__ sc, int M, int gb,
                                               const int* __restrict__ ei, int E,
                                               const int* __restrict__ flag,
                                               int* __restrict__ deg,
                                               int* __restrict__ dst32,
                                               uint2* __restrict__ sr,
                                               int interleave) {
    __shared__ float ldsf[6144];   // 3 x 8 KB (gemm path only)
    int bid;
    bool isGemm;
    if (interleave) {
        int g = blockIdx.x / 3, r = blockIdx.x % 3;
        if (r == 0) { isGemm = true; bid = g; }
        else        { isGemm = false; bid = g * 2 + r - 1; }
    } else {
        isGemm = (int)blockIdx.x < gb;
        bid = isGemm ? blockIdx.x : blockIdx.x - gb;
    }

    if (!isGemm) {
        int e = bid * 256 + threadIdx.x;
        if (e >= E) return;
        bool i64 = (flag[0] == 0);
        int s, d;
        if (i64) { s = ei[2 * e]; d = ei[2 * E + 2 * e]; }
        else     { s = ei[e];     d = ei[E + e]; }
        int r = atomicAdd(&deg[d], 1);
        dst32[e] = d;
        sr[e] = make_uint2((unsigned)s, (unsigned)r);
        return;
    }

    char* lds = (char*)ldsf;
    int t = threadIdx.x;
    int w = t >> 6, l = t & 63;
    int lr = l & 15, kg = l >> 4;
    int row0 = bid * 32;
    int colb = w * 48;

    f32x4 acc[2][3];
#pragma unroll
    for (int m = 0; m < 2; ++m)
#pragma unroll
        for (int nn = 0; nn < 3; ++nn) acc[m][nn] = (f32x4){0.f, 0.f, 0.f, 0.f};

    auto stage = [&](int kb, int buf) {
#pragma unroll
        for (int j = 0; j < 2; ++j) {
            int o = j * 4096 + t * 16;
            int row = o >> 8;
            int col4 = ((o >> 4) & 15) ^ (row & 15);
            int rowg = row0 + row;
            if (rowg >= M) rowg = M - 1;
            gload_lds16(X + (size_t)rowg * F_IN + kb + col4 * 4,
                        lds + buf * 8192 + j * 4096 + w * 1024);
        }
    };

    short8 breg[2][2][3];
    auto loadB = [&](int ts, int pp) {
#pragma unroll
        for (int kk = 0; kk < 2; ++kk)
#pragma unroll
            for (int nn = 0; nn < 3; ++nn)
                breg[pp][kk][nn] =
                    Bs[(size_t)(ts * 8 + kk * 4 + kg) * H1P + colb + nn * 16 + lr];
    };

    auto compute = [&](int cur, int pp) {
#pragma unroll
        for (int kk = 0; kk < 2; ++kk) {
            short8 a[2];
#pragma unroll
            for (int m = 0; m < 2; ++m) {
                int row = m * 16 + lr;
                char* base = lds + cur * 8192 + row * 256;
                int c0 = kk * 8 + kg * 2;
                float4 v0 = *(const float4*)(base + (((c0 + 0) ^ (row & 15)) * 16));
                float4 v1 = *(const float4*)(base + (((c0 + 1) ^ (row & 15)) * 16));
                union { unsigned u[4]; short8 s; } cu;
                cu.u[0] = cvtpk(v0.x, v0.y);
                cu.u[1] = cvtpk(v0.z, v0.w);
                cu.u[2] = cvtpk(v1.x, v1.y);
                cu.u[3] = cvtpk(v1.z, v1.w);
                a[m] = cu.s;
            }
#pragma unroll
            for (int m = 0; m < 2; ++m)
#pragma unroll
                for (int nn = 0; nn < 3; ++nn)
                    acc[m][nn] = __builtin_amdgcn_mfma_f32_16x16x32_bf16(
                        a[m], breg[pp][kk][nn], acc[m][nn], 0, 0, 0);
        }
    };

    stage(0, 0);
    stage(64, 1);
    loadB(0, 0);
    asm volatile("s_waitcnt vmcnt(8)" ::: "memory");
    __builtin_amdgcn_s_barrier();
    __builtin_amdgcn_sched_barrier(0);

#pragma unroll
    for (int ts = 0; ts < 8; ++ts) {
        if (ts < 6) stage((ts + 2) * 64, (ts + 2) % 3);
        if (ts < 7) loadB(ts + 1, (ts + 1) & 1);
        compute(ts % 3, ts & 1);
        if (ts < 7) {
            if (ts < 6) {
                asm volatile("s_waitcnt vmcnt(8)" ::: "memory");
            } else {
                asm volatile("s_waitcnt vmcnt(6)" ::: "memory");
            }
            __builtin_amdgcn_s_barrier();
            __builtin_amdgcn_sched_barrier(0);
        }
    }

    __syncthreads();
    float* rmaxp = (float*)lds;   // [32][4]
#pragma unroll
    for (int m = 0; m < 2; ++m) {
#pragma unroll
        for (int j = 0; j < 4; ++j) {
            int rl = m * 16 + kg * 4 + j;
            float lm = 0.f;
#pragma unroll
            for (int nn = 0; nn < 3; ++nn)
                lm = fmaxf(lm, fabsf(acc[m][nn][j]));
#pragma unroll
            for (int d = 1; d < 16; d <<= 1)
                lm = fmaxf(lm, __shfl_xor(lm, d));
            if (lr == 0) rmaxp[rl * 4 + w] = lm;
        }
    }
    __syncthreads();
#pragma unroll
    for (int m = 0; m < 2; ++m) {
#pragma unroll
        for (int j = 0; j < 4; ++j) {
            int rl = m * 16 + kg * 4 + j;
            int grow = row0 + rl;
            if (grow >= M) continue;
            float rm = fmaxf(fmaxf(rmaxp[rl * 4 + 0], rmaxp[rl * 4 + 1]),
                             fmaxf(rmaxp[rl * 4 + 2], rmaxp[rl * 4 + 3]));
            float inv = (rm > 0.f) ? 127.0f / rm : 0.f;
            if (w == 0 && lr == 0) sc[grow] = rm * (1.0f / 127.0f);
#pragma unroll
            for (int nn = 0; nn < 3; ++nn) {
                float v = acc[m][nn][j] * inv;
                v = fminf(fmaxf(rintf(v), -127.f), 127.f);
                Hq[(size_t)grow * H1P + colb + nn * 16 + lr] = (signed char)(int)v;
            }
        }
    }
}

// ---------------- scan1: prefix blocks + dinv + scd = sc*dinv --------------
__global__ void k_scan1(const int* __restrict__ deg, int* __restrict__ rp,
                        int* __restrict__ bsum, float* __restrict__ dinv,
                        const float* __restrict__ sc, float* __restrict__ scd,
                        int n) {
    __shared__ int s[256];
    int t = threadIdx.x;
    int base = blockIdx.x * 1024 + t * 4;
    int v0 = (base + 0 < n) ? deg[base + 0] : 0;
    int v1 = (base + 1 < n) ? deg[base + 1] : 0;
    int v2 = (base + 2 < n) ? deg[base + 2] : 0;
    int v3 = (base + 3 < n) ? deg[base + 3] : 0;
    if (base + 0 < n) { float d = rsqrtf((float)(v0 + 1)); dinv[base + 0] = d; scd[base + 0] = d * sc[base + 0]; }
    if (base + 1 < n) { float d = rsqrtf((float)(v1 + 1)); dinv[base + 1] = d; scd[base + 1] = d * sc[base + 1]; }
    if (base + 2 < n) { float d = rsqrtf((float)(v2 + 1)); dinv[base + 2] = d; scd[base + 2] = d * sc[base + 2]; }
    if (base + 3 < n) { float d = rsqrtf((float)(v3 + 1)); dinv[base + 3] = d; scd[base + 3] = d * sc[base + 3]; }
    int sum = v0 + v1 + v2 + v3;
    s[t] = sum;
    __syncthreads();
    for (int off = 1; off < 256; off <<= 1) {
        int x = (t >= off) ? s[t - off] : 0;
        __syncthreads();
        s[t] += x;
        __syncthreads();
    }
    int run = s[t] - sum;
    if (t == 255) bsum[blockIdx.x] = s[255];
    if (base + 0 < n) rp[base + 0] = run; run += v0;
    if (base + 1 < n) rp[base + 1] = run; run += v1;
    if (base + 2 < n) rp[base + 2] = run; run += v2;
    if (base + 3 < n) rp[base + 3] = run;
}

// ---------------- scan3: local bsum prefix (scan2 folded) + finalize -------
__global__ void k_scan3(const int* __restrict__ bsum, int* __restrict__ rp,
                        int n, int E, int nb) {
    __shared__ int s[128], ov[128];
    int t = threadIdx.x;
    if (t < 128) {
        int v = (t < nb) ? bsum[t] : 0;
        s[t] = v; ov[t] = v;
    }
    __syncthreads();
    for (int off = 1; off < 128; off <<= 1) {
        int x = 0;
        if (t < 128 && t >= off) x = s[t - off];
        __syncthreads();
        if (t < 128) s[t] += x;
        __syncthreads();
    }
    int i = blockIdx.x * 256 + t;
    if (i < n) {
        int b = i >> 10;
        rp[i] += s[b] - ov[b];
    } else if (i == n) {
        rp[n] = E;
    }
}

// ---------------- CSR fill: atomic-free, XCD-bucketed ----------------------
__global__ __launch_bounds__(256) void k_fill(const int* __restrict__ dst32,
                                              const uint2* __restrict__ sr, int E,
                                              const int* __restrict__ rp,
                                              int* __restrict__ csr,
                                              int bw, int chunk) {
    int bkt = blockIdx.x & 7;
    int lo = bkt * bw, hi = lo + bw;
    int ch = blockIdx.x >> 3;
    int e0 = ch * chunk;
    int e1 = min(E, e0 + chunk);
    for (int e = e0 + (int)threadIdx.x; e < e1; e += 256) {
        int d = dst32[e];
        if (d >= lo && d < hi) {
            uint2 v = sr[e];
            csr[rp[d] + (int)v.y] = (int)v.x;
        }
    }
}

// ---------------- CSR gather layer 1 on int8 rows (scd = sc*dinv) ----------
__global__ __launch_bounds__(256) void k_gat1q(const signed char* __restrict__ Hq,
                                               const float* __restrict__ scd,
                                               const float* __restrict__ dinv,
                                               const int* __restrict__ rp,
                                               const int* __restrict__ csr,
                                               const float* __restrict__ bias,
                                               uint2* __restrict__ out, int n) {
    int wv = threadIdx.x >> 6, l = threadIdx.x & 63;
    int i = blockIdx.x * 4 + wv;
    if (i >= n) return;
    bool act = l < 48;
    int c = act ? l : 0;
    const unsigned* Hr = (const unsigned*)(Hq + c * 4);

    float a0, a1, a2, a3;
    {
        unsigned w0 = Hr[(size_t)i * 48];
        float s0 = scd[i];
        a0 = (float)(signed char)(w0) * s0;
        a1 = (float)(signed char)(w0 >> 8) * s0;
        a2 = (float)(signed char)(w0 >> 16) * s0;
        a3 = (float)(signed char)(w0 >> 24) * s0;
    }
    float p0 = 0.f, p1 = 0.f, p2 = 0.f, p3 = 0.f;

    int e0 = rp[i], e1 = rp[i + 1];
    int e = e0;
    for (; e + 7 < e1; e += 8) {
        int s[8];
#pragma unroll
        for (int q = 0; q < 8; ++q) s[q] = csr[e + q];
        float scs[8];
#pragma unroll
        for (int q = 0; q < 8; ++q) scs[q] = scd[s[q]];
        unsigned v[8];
#pragma unroll
        for (int q = 0; q < 8; ++q) v[q] = Hr[(size_t)s[q] * 48];
#pragma unroll
        for (int q = 0; q < 8; q += 2) {
            a0 = fmaf((float)(signed char)(v[q]), scs[q], a0);
            a1 = fmaf((float)(signed char)(v[q] >> 8), scs[q], a1);
            a2 = fmaf((float)(signed char)(v[q] >> 16), scs[q], a2);
            a3 = fmaf((float)(signed char)(v[q] >> 24), scs[q], a3);
            p0 = fmaf((float)(signed char)(v[q + 1]), scs[q + 1], p0);
            p1 = fmaf((float)(signed char)(v[q + 1] >> 8), scs[q + 1], p1);
            p2 = fmaf((float)(signed char)(v[q + 1] >> 16), scs[q + 1], p2);
            p3 = fmaf((float)(signed char)(v[q + 1] >> 24), scs[q + 1], p3);
        }
    }
    for (; e < e1; ++e) {
        int s0 = csr[e];
        float sq = scd[s0];
        unsigned w0 = Hr[(size_t)s0 * 48];
        a0 = fmaf((float)(signed char)(w0), sq, a0);
        a1 = fmaf((float)(signed char)(w0 >> 8), sq, a1);
        a2 = fmaf((float)(signed char)(w0 >> 16), sq, a2);
        a3 = fmaf((float)(signed char)(w0 >> 24), sq, a3);
    }
    a0 += p0; a1 += p1; a2 += p2; a3 += p3;

    float di = dinv[i];
    float4 bb = *(const float4*)(bias + 4 * c);
    float o0 = fmaf(di, a0, bb.x);
    float o1 = fmaf(di, a1, bb.y);
    float o2 = fmaf(di, a2, bb.z);
    float o3 = fmaf(di, a3, bb.w);
    o0 = o0 >= 0.f ? o0 : 0.01f * o0;
    o1 = o1 >= 0.f ? o1 : 0.01f * o1;
    o2 = o2 >= 0.f ? o2 : 0.01f * o2;
    o3 = o3 >= 0.f ? o3 : 0.01f * o3;
    if (act) {
        uint2 r;
        r.x = (f2bf(o1) << 16) | f2bf(o0);
        r.y = (f2bf(o3) << 16) | f2bf(o2);
        out[(size_t)i * 48 + c] = r;
    }
}

// ---------------- GEMM2: h2' = dinv * (h1agg @ W2), bf16 in ---------------
__global__ __launch_bounds__(512) void k_gemm2(const unsigned short* __restrict__ A,
                                               const short8* __restrict__ Bs,
                                               const float* __restrict__ dinv,
                                               unsigned short* __restrict__ Hout,
                                               int M) {
    __shared__ unsigned short ldsu[16384];   // 2 x 16 KB
    char* lds = (char*)ldsu;
    int t = threadIdx.x;
    int w = t >> 6, l = t & 63;
    int lr = l & 15, kg = l >> 4;
    int wr = w >> 2, wc = w & 3;
    int row0 = blockIdx.x * 128;
    int colb = wc * 32;

    f32x4 acc[4][2];
#pragma unroll
    for (int m = 0; m < 4; ++m)
#pragma unroll
        for (int nn = 0; nn < 2; ++nn) acc[m][nn] = (f32x4){0.f, 0.f, 0.f, 0.f};

    auto stage = [&](int kb, int buf) {
#pragma unroll
        for (int j = 0; j < 2; ++j) {
            int o = j * 8192 + t * 16;
            int row = o >> 7;
            int chunk = ((o >> 4) & 7) ^ (row & 7);
            int rowg = row0 + row;
            if (rowg >= M) rowg = M - 1;
            gload_lds16(A + (size_t)rowg * H1P + kb + chunk * 8,
                        lds + buf * 16384 + j * 8192 + w * 1024);
        }
    };

    stage(0, 0);
    __syncthreads();

    for (int ts = 0; ts < 3; ++ts) {
        int cur = ts & 1;
        if (ts < 2) stage((ts + 1) * 64, cur ^ 1);
        short8 b[2][2];
#pragma unroll
        for (int kk = 0; kk < 2; ++kk)
#pragma unroll
            for (int nn = 0; nn < 2; ++nn)
                b[kk][nn] = Bs[(size_t)(ts * 8 + kk * 4 + kg) * H2P + colb + nn * 16 + lr];
        short8 a[2][4];
#pragma unroll
        for (int kk = 0; kk < 2; ++kk)
#pragma unroll
            for (int m = 0; m < 4; ++m) {
                int row = wr * 64 + m * 16 + lr;
                a[kk][m] = *(const short8*)(lds + cur * 16384 + row * 128 +
                                            (((kk * 4 + kg) ^ (row & 7)) * 16));
            }
#pragma unroll
        for (int kk = 0; kk < 2; ++kk)
#pragma unroll
            for (int m = 0; m < 4; ++m)
#pragma unroll
                for (int nn = 0; nn < 2; ++nn)
                    acc[m][nn] = __builtin_amdgcn_mfma_f32_16x16x32_bf16(a[kk][m], b[kk][nn], acc[m][nn], 0, 0, 0);
        __syncthreads();
    }

#pragma unroll
    for (int m = 0; m < 4; ++m) {
        int r4 = row0 + wr * 64 + m * 16 + kg * 4;
#pragma unroll
        for (int j = 0; j < 4; ++j) {
            int grow = r4 + j;
            if (grow < M) {
                float dv = dinv[grow];
#pragma unroll
                for (int nn = 0; nn < 2; ++nn)
                    Hout[(size_t)grow * H2P + colb + nn * 16 + lr] =
                        (unsigned short)f2bf(acc[m][nn][j] * dv);
            }
        }
    }
}

// ---------------- CSR gather layer 2 (CH=32, 2 nodes/wave, 8-deep ILP) -----
__global__ __launch_bounds__(256) void k_gat2(const uint2* __restrict__ H,
                                              const float* __restrict__ dinv,
                                              const int* __restrict__ rp,
                                              const int* __restrict__ csr,
                                              const float* __restrict__ bias,
                                              uint2* __restrict__ out, int n) {
    int wv = threadIdx.x >> 6, l = threadIdx.x & 63;
    int half = l >> 5, c = l & 31;
    int i = blockIdx.x * 8 + wv * 2 + half;
    if (i >= n) return;
    const uint2* Hr = H + c;

    float a0, a1, a2, a3;
    {
        uint2 v = Hr[(size_t)i * 32];
        a0 = BLO(v.x); a1 = BHI(v.x); a2 = BLO(v.y); a3 = BHI(v.y);
    }
    float p0 = 0.f, p1 = 0.f, p2 = 0.f, p3 = 0.f;

    int e0 = rp[i], e1 = rp[i + 1];
    int e = e0;
    for (; e + 7 < e1; e += 8) {
        int s[8];
#pragma unroll
        for (int q = 0; q < 8; ++q) s[q] = csr[e + q];
        uint2 v[8];
#pragma unroll
        for (int q = 0; q < 8; ++q) v[q] = Hr[(size_t)s[q] * 32];
#pragma unroll
        for (int q = 0; q < 8; q += 2) {
            a0 += BLO(v[q].x); a1 += BHI(v[q].x); a2 += BLO(v[q].y); a3 += BHI(v[q].y);
            p0 += BLO(v[q + 1].x); p1 += BHI(v[q + 1].x); p2 += BLO(v[q + 1].y); p3 += BHI(v[q + 1].y);
        }
    }
    for (; e + 3 < e1; e += 4) {
        int s0 = csr[e], s1 = csr[e + 1], s2 = csr[e + 2], s3 = csr[e + 3];
        uint2 va = Hr[(size_t)s0 * 32];
        uint2 vb = Hr[(size_t)s1 * 32];
        uint2 vc = Hr[(size_t)s2 * 32];
        uint2 vd = Hr[(size_t)s3 * 32];
        a0 += BLO(va.x); a1 += BHI(va.x); a2 += BLO(va.y); a3 += BHI(va.y);
        p0 += BLO(vb.x); p1 += BHI(vb.x); p2 += BLO(vb.y); p3 += BHI(vb.y);
        a0 += BLO(vc.x); a1 += BHI(vc.x); a2 += BLO(vc.y); a3 += BHI(vc.y);
        p0 += BLO(vd.x); p1 += BHI(vd.x); p2 += BLO(vd.y); p3 += BHI(vd.y);
    }
    for (; e < e1; ++e) {
        int s0 = csr[e];
        uint2 va = Hr[(size_t)s0 * 32];
        a0 += BLO(va.x); a1 += BHI(va.x); a2 += BLO(va.y); a3 += BHI(va.y);
    }
    a0 += p0; a1 += p1; a2 += p2; a3 += p3;

    float di = dinv[i];
    float4 bb = *(const float4*)(bias + 4 * c);
    float o0 = fmaf(di, a0, bb.x);
    float o1 = fmaf(di, a1, bb.y);
    float o2 = fmaf(di, a2, bb.z);
    float o3 = fmaf(di, a3, bb.w);
    o0 = o0 >= 0.f ? o0 : 0.01f * o0;
    o1 = o1 >= 0.f ? o1 : 0.01f * o1;
    o2 = o2 >= 0.f ? o2 : 0.01f * o2;
    o3 = o3 >= 0.f ? o3 : 0.01f * o3;
    uint2 r;
    r.x = (f2bf(o1) << 16) | f2bf(o0);
    r.y = (f2bf(o3) << 16) | f2bf(o2);
    out[(size_t)i * 32 + c] = r;
}

// ---------------- final layer: MFMA GEMM (128->64) + fused log_softmax -----
__global__ __launch_bounds__(256) void k_out(const unsigned short* __restrict__ H,
                                             const short8* __restrict__ Bs,
                                             const float* __restrict__ b3p,
                                             float* __restrict__ out, int M) {
    int t = threadIdx.x;
    int w = t >> 6, l = t & 63;
    int lr = l & 15, kg = l >> 4;
    int row0 = blockIdx.x * 64 + w * 16;

    f32x4 acc[4];
#pragma unroll
    for (int f = 0; f < 4; ++f) acc[f] = (f32x4){0.f, 0.f, 0.f, 0.f};

    int rowa = row0 + lr;
    if (rowa >= M) rowa = M - 1;
    const unsigned short* arow = H + (size_t)rowa * H2P;

#pragma unroll
    for (int ks = 0; ks < 4; ++ks) {
        short8 a = *(const short8*)(arow + ks * 32 + kg * 8);
#pragma unroll
        for (int f = 0; f < 4; ++f) {
            short8 b = Bs[(size_t)(ks * 4 + kg) * NCP + f * 16 + lr];
            acc[f] = __builtin_amdgcn_mfma_f32_16x16x32_bf16(a, b, acc[f], 0, 0, 0);
        }
    }

    float bl[4];
#pragma unroll
    for (int f = 0; f < 4; ++f) bl[f] = b3p[f * 16 + lr];

#pragma unroll
    for (int j = 0; j < 4; ++j) {
        int grow = row0 + kg * 4 + j;
        float lg[4];
#pragma unroll
        for (int f = 0; f < 4; ++f) lg[f] = acc[f][j] + bl[f];
        float m = fmaxf(fmaxf(lg[0], lg[1]), fmaxf(lg[2], lg[3]));
#pragma unroll
        for (int d = 1; d < 16; d <<= 1) m = fmaxf(m, __shfl_xor(m, d));
        float s = expf(lg[0] - m) + expf(lg[1] - m) + expf(lg[2] - m) + expf(lg[3] - m);
#pragma unroll
        for (int d = 1; d < 16; d <<= 1) s += __shfl_xor(s, d);
        float lse = m + logf(s);
        if (grow < M) {
#pragma unroll
            for (int f = 0; f < 4; ++f) {
                int c = f * 16 + lr;
                if (c < NC) out[(size_t)grow * NC + c] = lg[f] - lse;
            }
        }
    }
}

// ---------------------------------------------------------------------------
extern "C" void kernel_launch(void* const* d_in, const int* in_sizes, int n_in,
                              void* d_out, int out_size, void* d_ws, size_t ws_size,
                              hipStream_t stream) {
    const float* x  = (const float*)d_in[0];
    const int*   ei = (const int*)d_in[1];
    const float* W1 = (const float*)d_in[2];
    const float* b1 = (const float*)d_in[3];
    const float* W2 = (const float*)d_in[4];
    const float* b2 = (const float*)d_in[5];
    const float* W3 = (const float*)d_in[6];
    const float* b3 = (const float*)d_in[7];
    float* outp = (float*)d_out;

    int n = in_sizes[0] / F_IN;   // 100000
    int E = in_sizes[1] / 2;      // 1600000

    char* p = (char*)d_ws;
    auto alloc = [&](size_t bytes) -> char* {
        char* r = p;
        p += (bytes + 511) & ~(size_t)511;
        return r;
    };
    int*            fd     = (int*)alloc((size_t)(n + 1) * 4);
    int*            flag   = fd;
    int*            deg    = fd + 1;
    float*          dinv   = (float*)alloc((size_t)n * 4);
    int*            rp     = (int*)alloc((size_t)(n + 1) * 4);
    int*            bsum   = (int*)alloc(4096);
    int*            dst32  = (int*)alloc((size_t)E * 4);
    uint2*          sr     = (uint2*)alloc((size_t)E * 8);
    int*            csr    = (int*)alloc((size_t)E * 4);
    unsigned short* W1s    = (unsigned short*)alloc((size_t)F_IN * H1P * 2);
    unsigned short* W2s    = (unsigned short*)alloc((size_t)H1P * H2P * 2);
    unsigned short* W3s    = (unsigned short*)alloc((size_t)H2P * NCP * 2);
    float*          b1p    = (float*)alloc(H1P * 4);
    float*          b2p    = (float*)alloc(H2P * 4);
    float*          b3p    = (float*)alloc(NCP * 4);
    signed char*    h1q    = (signed char*)alloc((size_t)n * H1P);
    float*          sc     = (float*)alloc((size_t)n * 4);
    float*          scd    = (float*)alloc((size_t)n * 4);
    unsigned short* h1agg  = (unsigned short*)alloc((size_t)n * H1P * 2);
    unsigned short* h2     = (unsigned short*)alloc((size_t)n * H2P * 2);
    unsigned short* h2agg  = (unsigned short*)alloc((size_t)n * H2P * 2);

    hipMemsetAsync(fd, 0, (size_t)(n + 1) * 4, stream);

    k_init<<<530, 256, 0, stream>>>(ei, flag, W1, W2, W3, b1, b2, b3,
                                    W1s, W2s, W3s, b1p, b2p, b3p);

    int gb = (n + 31) / 32;
    int eb = (E + 255) / 256;
    int interleave = (eb == 2 * gb) ? 1 : 0;
    k_megaA<<<gb + eb, 256, 0, stream>>>(x, (const short8*)W1s, h1q, sc, n, gb,
                                         ei, E, flag, deg, dst32, sr, interleave);

    int nb = (n + 1023) / 1024;
    k_scan1<<<nb, 256, 0, stream>>>(deg, rp, bsum, dinv, sc, scd, n);
    k_scan3<<<(n + 1 + 255) / 256, 256, 0, stream>>>(bsum, rp, n, E, nb);

    int bw = (n + 7) / 8;
    int nch = 256;
    int chunk = (E + nch - 1) / nch;
    k_fill<<<nch * 8, 256, 0, stream>>>(dst32, sr, E, rp, csr, bw, chunk);

    // layer-1 gather on int8 rows (scd-scaled) -> bf16 h1agg
    k_gat1q<<<(n + 3) / 4, 256, 0, stream>>>(h1q, scd, dinv, rp, csr, b1p,
                                             (uint2*)h1agg, n);
    // layer 2
    k_gemm2<<<(n + 127) / 128, 512, 0, stream>>>(h1agg, (const short8*)W2s, dinv, h2, n);
    k_gat2<<<(n + 7) / 8, 256, 0, stream>>>((const uint2*)h2, dinv, rp, csr, b2p,
                                            (uint2*)h2agg, n);
    // output layer + log_softmax (MFMA, fused)
    k_out<<<(n + 63) / 64, 256, 0, stream>>>(h2agg, (const short8*)W3s, b3p, outp, n);
}